// Round 1
// baseline (564.483 us; speedup 1.0000x reference)
//
#include <hip/hip_runtime.h>
#include <cmath>

#define IMG_H 128
#define IMG_W 128

// ---------------------------------------------------------------------------
// Kernel 1: fused per-group offset/mask conv + deformable sampling + group conv
// grid: (64 tiles, 8 groups, 4 batch), block: (16,16)
// Writes target (b,64,h,w) into `target` (= d_out).
// ---------------------------------------------------------------------------
__global__ __launch_bounds__(256) void deform_kernel(
    const float* __restrict__ o, const float* __restrict__ anchor,
    const float* __restrict__ pw, const float* __restrict__ pb,
    const float* __restrict__ mw, const float* __restrict__ mb,
    const float* __restrict__ cw, float* __restrict__ target)
{
    const int tile = blockIdx.x;      // 0..63 (8x8 tiles of 16x16)
    const int g = blockIdx.y;         // 0..7
    const int b = blockIdx.z;         // 0..3
    const int tile_y = tile >> 3, tile_x = tile & 7;
    const int tx = threadIdx.x, ty = threadIdx.y;
    const int t = ty * 16 + tx;

    __shared__ float sf[8 * 18 * 18];   // motion slice tile + halo (zero-padded)

    const float* fbase = o + (((size_t)(b * 64 + g * 8)) << 14);
    for (int idx = t; idx < 8 * 324; idx += 256) {
        int ic = idx / 324; int r = idx - ic * 324;
        int iy = r / 18;    int ix = r - iy * 18;
        int gy = tile_y * 16 + iy - 1, gx = tile_x * 16 + ix - 1;
        float v = 0.f;
        if (gy >= 0 && gy < IMG_H && gx >= 0 && gx < IMG_W)
            v = fbase[(ic << 14) + (gy << 7) + gx];
        sf[idx] = v;
    }
    __syncthreads();

    const float* pwg = pw + g * 18 * 72;   // (18, 8, 9)
    const float* pbg = pb + g * 18;
    const float* mwg = mw + g * 9 * 72;    // (9, 8, 9)
    const float* mbg = mb + g * 9;
    const float* cwg = cw + g * 8 * 72;    // (8, 8, 9)

    // 27 conv outputs per pixel: ox[9] (row offsets), oy[9] (col offsets), mz[9] (mask pre-sigmoid)
    float ox[9], oy[9], mz[9];
    #pragma unroll
    for (int n = 0; n < 9; ++n) { ox[n] = pbg[n]; oy[n] = pbg[9 + n]; mz[n] = mbg[n]; }

    #pragma unroll
    for (int ic = 0; ic < 8; ++ic) {
        #pragma unroll
        for (int k = 0; k < 9; ++k) {
            const int ky = k / 3, kx = k - (k / 3) * 3;
            float fv = sf[ic * 324 + (ty + ky) * 18 + (tx + kx)];
            #pragma unroll
            for (int n = 0; n < 9; ++n) {
                ox[n] = fmaf(fv, pwg[(n * 8 + ic) * 9 + k], ox[n]);
                oy[n] = fmaf(fv, pwg[((9 + n) * 8 + ic) * 9 + k], oy[n]);
                mz[n] = fmaf(fv, mwg[(n * 8 + ic) * 9 + k], mz[n]);
            }
        }
    }

    const int gy = tile_y * 16 + ty, gx = tile_x * 16 + tx;
    const float* xb = anchor + (((size_t)(b * 64 + g * 8)) << 14);

    float acc[8] = {0.f, 0.f, 0.f, 0.f, 0.f, 0.f, 0.f, 0.f};
    #pragma unroll
    for (int n = 0; n < 9; ++n) {
        // p0 starts at 1, pn in {-1,0,1}: px = gy + n/3 + off_x, py = gx + n%3 + off_y
        float pxf = (float)(gy + (n / 3)) + ox[n];
        float pyf = (float)(gx + (n % 3)) + oy[n];
        float fx = floorf(pxf), fy = floorf(pyf);
        float qxl = fminf(fmaxf(fx, 0.f), 127.f);
        float qxr = fminf(fmaxf(fx + 1.f, 0.f), 127.f);
        float qyl = fminf(fmaxf(fy, 0.f), 127.f);
        float qyr = fminf(fmaxf(fy + 1.f, 0.f), 127.f);
        float pxc = fminf(fmaxf(pxf, 0.f), 127.f);
        float pyc = fminf(fmaxf(pyf, 0.f), 127.f);
        float glx = 1.f + (qxl - pxc), grx = 1.f - (qxr - pxc);
        float gly = 1.f + (qyl - pyc), gry = 1.f - (qyr - pyc);
        float mm = 1.f / (1.f + expf(-mz[n]));
        float wlt = glx * gly * mm, wrb = grx * gry * mm;
        float wlb = glx * gry * mm, wrt = grx * gly * mm;
        int olt = (((int)qxl) << 7) + (int)qyl;
        int orb = (((int)qxr) << 7) + (int)qyr;
        int olb = (((int)qxl) << 7) + (int)qyr;
        int ort = (((int)qxr) << 7) + (int)qyl;
        #pragma unroll
        for (int ic = 0; ic < 8; ++ic) {
            const float* xc = xb + (ic << 14);
            float v = wlt * xc[olt] + wrb * xc[orb] + wlb * xc[olb] + wrt * xc[ort];
            #pragma unroll
            for (int oc = 0; oc < 8; ++oc)
                acc[oc] = fmaf(v, cwg[(oc * 8 + ic) * 9 + n], acc[oc]);
        }
    }

    float* tb = target + (((size_t)(b * 64 + g * 8)) << 14) + (gy << 7) + gx;
    #pragma unroll
    for (int oc = 0; oc < 8; ++oc) tb[(size_t)oc << 14] = acc[oc];
}

// ---------------------------------------------------------------------------
// Kernel 2/3: 3x3 conv, pad 1, Cin = nchunk*8 channels (concat of inA then inB),
// 64 out channels, + bias, optional residual add.
// grid: (64 tiles, 2 oc-halves, 4 batch), block: 256 (4 waves, each 8 oc).
// Each thread: 4 pixels x 8 oc accumulators.
// ---------------------------------------------------------------------------
__global__ __launch_bounds__(256) void conv3x3_kernel(
    const float* __restrict__ inA, const float* __restrict__ inB, int cinA, int nchunk,
    const float* __restrict__ w, const float* __restrict__ bias,
    const float* __restrict__ residual, float* __restrict__ out)
{
    const int tile = blockIdx.x;     // 0..63
    const int ochalf = blockIdx.y;   // 0..1
    const int b = blockIdx.z;
    const int tile_y = tile >> 3, tile_x = tile & 7;
    const int t = threadIdx.x;
    const int wave = t >> 6, lane = t & 63;
    const int px = lane & 15, py0 = lane >> 4;   // pixel rows py0+4q, col px
    const int cin = nchunk * 8;

    __shared__ float sin_[8 * 324];   // 8 ch x 18x18 input tile chunk
    __shared__ float sw[72 * 32];     // weights: [ic*9+k][oc(32)]

    float acc[4][8];
    #pragma unroll
    for (int q = 0; q < 4; ++q)
        #pragma unroll
        for (int oo = 0; oo < 8; ++oo) acc[q][oo] = 0.f;

    for (int c = 0; c < nchunk; ++c) {
        __syncthreads();
        for (int idx = t; idx < 8 * 324; idx += 256) {
            int ic = idx / 324; int r = idx - ic * 324;
            int iy = r / 18;    int ix = r - iy * 18;
            int gy = tile_y * 16 + iy - 1, gx = tile_x * 16 + ix - 1;
            int ch = c * 8 + ic;
            const float* src = (ch < cinA)
                ? (inA + (((size_t)(b * 64 + ch)) << 14))
                : (inB + (((size_t)(b * 64 + ch - cinA)) << 14));
            float v = 0.f;
            if (gy >= 0 && gy < IMG_H && gx >= 0 && gx < IMG_W) v = src[(gy << 7) + gx];
            sin_[idx] = v;
        }
        for (int idx = t; idx < 72 * 32; idx += 256) {
            int oc = idx & 31; int ick = idx >> 5;
            int ic = ick / 9;  int k = ick - ic * 9;
            sw[idx] = w[((size_t)(ochalf * 32 + oc) * cin + c * 8 + ic) * 9 + k];
        }
        __syncthreads();

        #pragma unroll
        for (int ic = 0; ic < 8; ++ic) {
            #pragma unroll
            for (int k = 0; k < 9; ++k) {
                const int ky = k / 3, kx = k - (k / 3) * 3;
                const float* wp = &sw[(ic * 9 + k) * 32 + wave * 8];
                float wv[8];
                #pragma unroll
                for (int oo = 0; oo < 8; ++oo) wv[oo] = wp[oo];
                #pragma unroll
                for (int q = 0; q < 4; ++q) {
                    float v = sin_[ic * 324 + (py0 + 4 * q + ky) * 18 + (px + kx)];
                    #pragma unroll
                    for (int oo = 0; oo < 8; ++oo)
                        acc[q][oo] = fmaf(v, wv[oo], acc[q][oo]);
                }
            }
        }
    }

    const int oc0 = ochalf * 32 + wave * 8;
    #pragma unroll
    for (int oo = 0; oo < 8; ++oo) {
        float bo = bias[oc0 + oo];
        #pragma unroll
        for (int q = 0; q < 4; ++q) {
            int gy = tile_y * 16 + py0 + 4 * q, gx = tile_x * 16 + px;
            size_t idx = (((size_t)(b * 64 + oc0 + oo)) << 14) + (gy << 7) + gx;
            float val = acc[q][oo] + bo;
            if (residual) val += residual[idx];
            out[idx] = val;
        }
    }
}

// ---------------------------------------------------------------------------
extern "C" void kernel_launch(void* const* d_in, const int* in_sizes, int n_in,
                              void* d_out, int out_size, void* d_ws, size_t ws_size,
                              hipStream_t stream) {
    const float* o      = (const float*)d_in[0];
    const float* anchor = (const float*)d_in[1];
    const float* pw     = (const float*)d_in[2];
    const float* pb     = (const float*)d_in[3];
    const float* mw     = (const float*)d_in[4];
    const float* mb     = (const float*)d_in[5];
    const float* cw     = (const float*)d_in[6];
    const float* w1     = (const float*)d_in[7];
    const float* b1     = (const float*)d_in[8];
    const float* w2     = (const float*)d_in[9];
    const float* b2     = (const float*)d_in[10];

    float* out = (float*)d_out;
    float* target = out;          // deform output lives in d_out (fully overwritten)
    float* t1 = (float*)d_ws;     // conv1 output: 4*64*128*128 floats = 16.78 MB

    // Stage 1+2: deformable group conv -> target
    deform_kernel<<<dim3(64, 8, 4), dim3(16, 16), 0, stream>>>(
        o, anchor, pw, pb, mw, mb, cw, target);

    // Stage 3a: conv1 over concat(target, anchor), 128 -> 64, +b1
    conv3x3_kernel<<<dim3(64, 2, 4), 256, 0, stream>>>(
        target, anchor, 64, 16, w1, b1, nullptr, t1);

    // Stage 3b: conv2 64 -> 64, +b2, + residual(target)  (in-place safe: same-index RMW per thread)
    conv3x3_kernel<<<dim3(64, 2, 4), 256, 0, stream>>>(
        t1, nullptr, 64, 8, w2, b2, target, out);
}

// Round 3
// 208.409 us; speedup vs baseline: 2.7085x; 2.7085x over previous
//
#include <hip/hip_runtime.h>

// ============================================================================
// MotionCompensation on MI355X — bf16 MFMA pipeline, precision-fixed.
// Offset/mask conv runs in split-bf16 (hi+lo) 3-MFMA form => ~f32-accurate
// offsets, eliminating floor() flips at the sampler's clip boundary.
// ============================================================================

typedef __attribute__((ext_vector_type(8))) short short8;
typedef __attribute__((ext_vector_type(4))) float float4v;

#define MFMA_B16(a, b, c) __builtin_amdgcn_mfma_f32_16x16x32_bf16(a, b, c, 0, 0, 0)

__device__ __forceinline__ ushort f2bf(float f) {          // RNE f32 -> bf16
    union { float f; unsigned u; } v; v.f = f;
    unsigned r = v.u + 0x7FFFu + ((v.u >> 16) & 1u);
    return (ushort)(r >> 16);
}
__device__ __forceinline__ float bf2f(ushort h) {
    union { unsigned u; float f; } v; v.u = ((unsigned)h) << 16;
    return v.f;
}

// ---------------------------------------------------------------------------
// Weight repack:
//   rw1[s9][oc64][ic128]  rw2[s9][oc64][ic64]  (bf16)
//   rpwh/rpwl[g8][n32][k96]  hi/lo split (n: 0-8 ox, 9-17 oy, 18-26 mz;
//                            k = s*8+ic, k==72 bias)
//   rcw[g8][oc16][k96] (k = n*8+ic)
// ---------------------------------------------------------------------------
__global__ __launch_bounds__(256) void repack_weights(
    const float* __restrict__ w1, const float* __restrict__ w2,
    const float* __restrict__ pw, const float* __restrict__ pb,
    const float* __restrict__ mw, const float* __restrict__ mb,
    const float* __restrict__ cw,
    ushort* __restrict__ rw1, ushort* __restrict__ rw2,
    ushort* __restrict__ rpwh, ushort* __restrict__ rpwl,
    ushort* __restrict__ rcw)
{
    int i = blockIdx.x * 256 + threadIdx.x;
    if (i < 73728) {                       // rw1
        int ic = i & 127, r = i >> 7, oc = r & 63, s = r >> 6;
        rw1[i] = f2bf(w1[(oc * 128 + ic) * 9 + s]);
    }
    if (i < 36864) {                       // rw2
        int ic = i & 63, r = i >> 6, oc = r & 63, s = r >> 6;
        rw2[i] = f2bf(w2[(oc * 64 + ic) * 9 + s]);
    }
    if (i < 24576) {                       // rpw hi/lo
        int k = i % 96, r = i / 96, n = r & 31, g = r >> 5;
        float v = 0.f;
        if (k < 72) {
            int s = k >> 3, ic = k & 7;
            if (n < 18)      v = pw[((g * 18 + n) * 8 + ic) * 9 + s];
            else if (n < 27) v = mw[((g * 9 + (n - 18)) * 8 + ic) * 9 + s];
        } else if (k == 72) {
            if (n < 18)      v = pb[g * 18 + n];
            else if (n < 27) v = mb[g * 9 + (n - 18)];
        }
        ushort h = f2bf(v);
        rpwh[i] = h;
        rpwl[i] = f2bf(v - bf2f(h));
    }
    if (i < 12288) {                       // rcw
        int k = i % 96, r = i / 96, oc = r & 15, g = r >> 4;
        float v = 0.f;
        if (k < 72 && oc < 8) {
            int n = k >> 3, ic = k & 7;
            v = cw[((g * 8 + oc) * 8 + ic) * 9 + n];
        }
        rcw[i] = f2bf(v);
    }
}

// ---------------------------------------------------------------------------
// NCHW f32 -> NHWC bf16 (anchor only). grid (64, 4 batch)
// ---------------------------------------------------------------------------
__global__ __launch_bounds__(256) void to_nhwc(
    const float* __restrict__ anchor, ushort* __restrict__ anc_nhwc)
{
    int pix = blockIdx.x * 256 + threadIdx.x;
    int b = blockIdx.y;
    ushort tmp[64];
    #pragma unroll
    for (int ch = 0; ch < 64; ++ch)
        tmp[ch] = f2bf(anchor[(((size_t)(b * 64 + ch)) << 14) + pix]);
    ushort* dp = anc_nhwc + (((size_t)b) << 20) + (size_t)pix * 64;
    #pragma unroll
    for (int grp = 0; grp < 8; ++grp) {
        short8 v;
        #pragma unroll
        for (int j = 0; j < 8; ++j) v[j] = (short)tmp[grp * 8 + j];
        *(short8*)(dp + grp * 8) = v;
    }
}

// ---------------------------------------------------------------------------
// Deformable stage, 3 phases per (16x16 tile, group, batch):
//  A: offset/mask conv via split-bf16 3-MFMA (K=96 padded, bias at k=72)
//  B: per-thread bilinear sampling from NHWC bf16 anchor
//  C: 8x8x9 group conv via MFMA (K=96 padded)
// Writes target f32 NCHW (=d_out) and xcatA bf16 NHWC (conv1 input ch 0-63).
// ---------------------------------------------------------------------------
__global__ __launch_bounds__(256, 2) void deform_mfma(
    const float* __restrict__ o, const ushort* __restrict__ anc,
    const ushort* __restrict__ rpwh, const ushort* __restrict__ rpwl,
    const ushort* __restrict__ rcw,
    ushort* __restrict__ xcatA, float* __restrict__ target)
{
    const int tile = blockIdx.x, g = blockIdx.y, b = blockIdx.z;
    const int ty0 = (tile >> 3) * 16, tx0 = (tile & 7) * 16;
    const int tid = threadIdx.x, lane = tid & 63, wave = tid >> 6;
    const int l15 = lane & 15, quad = lane >> 4;

    __shared__ __align__(16) ushort slabh[324 * 8];   // o tile hi, 18x18 halo
    __shared__ __align__(16) ushort slabl[324 * 8];   // o tile lo
    __shared__ __align__(16) ushort sU[256 * 104];    // union: sOff / sS / sD

    const size_t nbase = ((size_t)b) << 20;           // per-image NHWC elems

    for (int idx = tid; idx < 8 * 324; idx += 256) {
        int ic = idx / 324; int pix = idx - ic * 324;
        int r = pix / 18, c = pix - r * 18;
        int gy = ty0 + r - 1, gx = tx0 + c - 1;
        float v = 0.f;
        if ((unsigned)gy < 128u && (unsigned)gx < 128u)
            v = o[(((size_t)(b * 64 + g * 8 + ic)) << 14) + (gy << 7) + gx];
        ushort h = f2bf(v);
        slabh[pix * 8 + ic] = h;
        slabl[pix * 8 + ic] = f2bf(v - bf2f(h));
    }
    __syncthreads();

    // ---- phase A: offsets/mask conv (27 out ch padded to 32), hi/lo split
    float4v offacc[4][2] = {};
    #pragma unroll
    for (int ks = 0; ks < 3; ++ks) {
        short8 Bh[2], Bl[2];
        #pragma unroll
        for (int nf = 0; nf < 2; ++nf) {
            int off = (g * 32 + nf * 16 + l15) * 96 + ks * 32 + quad * 8;
            Bh[nf] = *(const short8*)(rpwh + off);
            Bl[nf] = *(const short8*)(rpwl + off);
        }
        short8 Ah[4], Al[4];
        if (ks < 2) {
            int s = ks * 4 + quad, sy = s / 3, sx = s - sy * 3;
            #pragma unroll
            for (int py = 0; py < 4; ++py) {
                int row = wave * 4 + py;
                int sl = ((row + sy) * 18 + l15 + sx) * 8;
                Ah[py] = *(const short8*)(&slabh[sl]);
                Al[py] = *(const short8*)(&slabl[sl]);
            }
        } else {  // k 64-71: tap s=8 (quad0); k72: bias one-hot (quad1)
            #pragma unroll
            for (int py = 0; py < 4; ++py) {
                short8 zh = {0, 0, 0, 0, 0, 0, 0, 0};
                short8 zl = {0, 0, 0, 0, 0, 0, 0, 0};
                if (quad == 0) {
                    int row = wave * 4 + py;
                    int sl = ((row + 2) * 18 + l15 + 2) * 8;
                    zh = *(const short8*)(&slabh[sl]);
                    zl = *(const short8*)(&slabl[sl]);
                } else if (quad == 1) {
                    zh[0] = (short)0x3F80;  // bf16 1.0 (bias column)
                }
                Ah[py] = zh; Al[py] = zl;
            }
        }
        #pragma unroll
        for (int py = 0; py < 4; ++py)
            #pragma unroll
            for (int nf = 0; nf < 2; ++nf) {
                offacc[py][nf] = MFMA_B16(Ah[py], Bh[nf], offacc[py][nf]);
                offacc[py][nf] = MFMA_B16(Ah[py], Bl[nf], offacc[py][nf]);
                offacc[py][nf] = MFMA_B16(Al[py], Bh[nf], offacc[py][nf]);
            }
    }
    // bounce D (px = quad*4+reg, ch = nf*16+l15) -> sOff[p][33]
    float* sOff = (float*)sU;
    #pragma unroll
    for (int py = 0; py < 4; ++py) {
        int p0 = (wave * 4 + py) * 16 + quad * 4;
        #pragma unroll
        for (int nf = 0; nf < 2; ++nf)
            #pragma unroll
            for (int reg = 0; reg < 4; ++reg)
                sOff[(p0 + reg) * 33 + nf * 16 + l15] = offacc[py][nf][reg];
    }
    __syncthreads();

    const int p = tid;
    const int gy = ty0 + (p >> 4), gx = tx0 + (p & 15);
    float ox[9], oy[9], mz[9];
    #pragma unroll
    for (int n = 0; n < 9; ++n) {
        ox[n] = sOff[p * 33 + n];
        oy[n] = sOff[p * 33 + 9 + n];
        mz[n] = sOff[p * 33 + 18 + n];
    }
    __syncthreads();  // sOff dead; sS (same memory) may now be written

    // ---- phase B: bilinear sampling -> sS[p][k=n*8+ic] bf16 (stride 104)
    #pragma unroll
    for (int n = 0; n < 9; ++n) {
        float pxf = (float)(gy + n / 3) + ox[n];
        float pyf = (float)(gx + n % 3) + oy[n];
        float fx = floorf(pxf), fy = floorf(pyf);
        float qxl = fminf(fmaxf(fx, 0.f), 127.f);
        float qxr = fminf(fmaxf(fx + 1.f, 0.f), 127.f);
        float qyl = fminf(fmaxf(fy, 0.f), 127.f);
        float qyr = fminf(fmaxf(fy + 1.f, 0.f), 127.f);
        float pxc = fminf(fmaxf(pxf, 0.f), 127.f);
        float pyc = fminf(fmaxf(pyf, 0.f), 127.f);
        float glx = 1.f + (qxl - pxc), grx = 1.f - (qxr - pxc);
        float gly = 1.f + (qyl - pyc), gry = 1.f - (qyr - pyc);
        float mm = 1.f / (1.f + expf(-mz[n]));
        float wlt = glx * gly * mm, wrb = grx * gry * mm;
        float wlb = glx * gry * mm, wrt = grx * gly * mm;
        int ixl = (int)qxl, ixr = (int)qxr, iyl = (int)qyl, iyr = (int)qyr;
        const ushort* ab = anc + nbase + g * 8;
        short8 vlt = *(const short8*)(ab + (size_t)(ixl * 128 + iyl) * 64);
        short8 vrb = *(const short8*)(ab + (size_t)(ixr * 128 + iyr) * 64);
        short8 vlb = *(const short8*)(ab + (size_t)(ixl * 128 + iyr) * 64);
        short8 vrt = *(const short8*)(ab + (size_t)(ixr * 128 + iyl) * 64);
        short8 sv;
        #pragma unroll
        for (int ic = 0; ic < 8; ++ic) {
            float val = wlt * bf2f((ushort)vlt[ic]) + wrb * bf2f((ushort)vrb[ic])
                      + wlb * bf2f((ushort)vlb[ic]) + wrt * bf2f((ushort)vrt[ic]);
            sv[ic] = (short)f2bf(val);
        }
        *(short8*)(&sU[p * 104 + n * 8]) = sv;
    }
    {
        short8 z = {0, 0, 0, 0, 0, 0, 0, 0};
        *(short8*)(&sU[p * 104 + 72]) = z;
        *(short8*)(&sU[p * 104 + 80]) = z;
        *(short8*)(&sU[p * 104 + 88]) = z;
    }
    __syncthreads();

    // ---- phase C: group conv, N = 16 (8 used), K = 96 (72 used)
    float4v cacc[4] = {};
    #pragma unroll
    for (int ks = 0; ks < 3; ++ks) {
        short8 Bw = *(const short8*)(rcw + ((g * 16 + l15) * 96 + ks * 32 + quad * 8));
        #pragma unroll
        for (int py = 0; py < 4; ++py) {
            int pp = (wave * 4 + py) * 16 + l15;
            short8 Af = *(const short8*)(&sU[pp * 104 + ks * 32 + quad * 8]);
            cacc[py] = MFMA_B16(Af, Bw, cacc[py]);
        }
    }
    __syncthreads();
    // bounce D (px = quad*4+reg, oc = l15<8) into head of own sS rows
    #pragma unroll
    for (int py = 0; py < 4; ++py) {
        int pr = (wave * 4 + py) * 16 + quad * 4;
        if (l15 < 8) {
            #pragma unroll
            for (int reg = 0; reg < 4; ++reg)
                ((float*)&sU[(pr + reg) * 104])[l15] = cacc[py][reg];
        }
    }
    __syncthreads();
    float res[8];
    #pragma unroll
    for (int oc = 0; oc < 8; ++oc) res[oc] = ((float*)&sU[p * 104])[oc];

    short8 pk;
    #pragma unroll
    for (int oc = 0; oc < 8; ++oc) pk[oc] = (short)f2bf(res[oc]);
    *(short8*)(xcatA + nbase + (size_t)(gy * 128 + gx) * 64 + g * 8) = pk;
    #pragma unroll
    for (int oc = 0; oc < 8; ++oc)
        target[(((size_t)(b * 64 + g * 8 + oc)) << 14) + gy * 128 + gx] = res[oc];
}

// ---------------------------------------------------------------------------
// conv1: 3x3, cin=128 (xcatA ch0-63 | anchor ch64-127), cout=64, +bias.
// Implicit GEMM: A = pixels (LDS NHWC halo patch), B = rw1 frags from global.
// Patch 16w x 8h; wave = 4 pixel rows x 32 oc. Output t1 NHWC bf16.
// ---------------------------------------------------------------------------
__global__ __launch_bounds__(256, 2) void conv1_mfma(
    const ushort* __restrict__ xA, const ushort* __restrict__ xB,
    const ushort* __restrict__ rw1, const float* __restrict__ b1,
    ushort* __restrict__ t1)
{
    const int patch = blockIdx.x, b = blockIdx.y;
    const int px0 = (patch & 7) * 16, py0 = (patch >> 3) * 8;
    const int tid = threadIdx.x, lane = tid & 63, wave = tid >> 6;
    const int mhalf = wave & 1, nhalf = wave >> 1;
    const int l15 = lane & 15, quad = lane >> 4;

    __shared__ __align__(16) ushort sA[180 * 136];    // 18x10 halo, 128ch +8 pad

    const size_t nbase = ((size_t)b) << 20;
    for (int task = tid; task < 2880; task += 256) {  // 180 px * 16 ch-groups
        int pix = task >> 4, grp = task & 15;
        int r = pix / 18, c = pix - r * 18;
        int gy = py0 + r - 1, gx = px0 + c - 1;
        short8 v = {0, 0, 0, 0, 0, 0, 0, 0};
        if ((unsigned)gy < 128u && (unsigned)gx < 128u) {
            const ushort* src = (grp < 8) ? xA : xB;
            v = *(const short8*)(src + nbase + (size_t)(gy * 128 + gx) * 64 + (grp & 7) * 8);
        }
        *(short8*)(&sA[pix * 136 + grp * 8]) = v;
    }
    __syncthreads();

    float4v acc[4][2] = {};                           // [py][nf]
    #pragma unroll
    for (int ks = 0; ks < 4; ++ks) {
        short8 B[9][2];
        #pragma unroll
        for (int s = 0; s < 9; ++s)
            #pragma unroll
            for (int nf = 0; nf < 2; ++nf) {
                int oc = nhalf * 32 + nf * 16 + l15;
                B[s][nf] = *(const short8*)(rw1 + ((s * 64 + oc) * 128 + ks * 32 + quad * 8));
            }
        #pragma unroll
        for (int r = 0; r < 6; ++r) {                 // slab row = py + ky
            int slabrow = mhalf * 4 + r;
            short8 A[3];
            #pragma unroll
            for (int kx = 0; kx < 3; ++kx)
                A[kx] = *(const short8*)(&sA[(slabrow * 18 + l15 + kx) * 136 + ks * 32 + quad * 8]);
            #pragma unroll
            for (int ky = 0; ky < 3; ++ky) {
                int py = r - ky;
                if (py >= 0 && py < 4) {
                    #pragma unroll
                    for (int kx = 0; kx < 3; ++kx)
                        #pragma unroll
                        for (int nf = 0; nf < 2; ++nf)
                            acc[py][nf] = MFMA_B16(A[kx], B[ky * 3 + kx][nf], acc[py][nf]);
                }
            }
        }
    }
    // epilogue: D px = quad*4+reg, oc = nhalf*32+nf*16+l15 -> t1 NHWC bf16
    #pragma unroll
    for (int nf = 0; nf < 2; ++nf) {
        int oc = nhalf * 32 + nf * 16 + l15;
        float bias = b1[oc];
        #pragma unroll
        for (int py = 0; py < 4; ++py) {
            int gy = py0 + mhalf * 4 + py;
            #pragma unroll
            for (int reg = 0; reg < 4; ++reg) {
                int gx = px0 + quad * 4 + reg;
                t1[nbase + (size_t)(gy * 128 + gx) * 64 + oc] = f2bf(acc[py][nf][reg] + bias);
            }
        }
    }
}

// ---------------------------------------------------------------------------
// conv2: 3x3, cin=64 (t1), cout=64, +bias +residual(target). A/B roles
// swapped (A = weights) so D[oc][px] -> coalesced f32 NCHW stores.
// outres aliases target (same-index RMW per thread: safe).
// ---------------------------------------------------------------------------
__global__ __launch_bounds__(256, 2) void conv2_mfma(
    const ushort* __restrict__ t1, const ushort* __restrict__ rw2,
    const float* __restrict__ b2, float* outres)
{
    const int patch = blockIdx.x, b = blockIdx.y;
    const int px0 = (patch & 7) * 16, py0 = (patch >> 3) * 8;
    const int tid = threadIdx.x, lane = tid & 63, wave = tid >> 6;
    const int ohalf = wave & 1, rhalf = wave >> 1;
    const int l15 = lane & 15, quad = lane >> 4;

    __shared__ __align__(16) ushort sX[180 * 72];     // 18x10 halo, 64ch +8 pad

    const size_t nbase = ((size_t)b) << 20;
    for (int task = tid; task < 1440; task += 256) {  // 180 px * 8 ch-groups
        int pix = task >> 3, grp = task & 7;
        int r = pix / 18, c = pix - r * 18;
        int gy = py0 + r - 1, gx = px0 + c - 1;
        short8 v = {0, 0, 0, 0, 0, 0, 0, 0};
        if ((unsigned)gy < 128u && (unsigned)gx < 128u)
            v = *(const short8*)(t1 + nbase + (size_t)(gy * 128 + gx) * 64 + grp * 8);
        *(short8*)(&sX[pix * 72 + grp * 8]) = v;
    }
    __syncthreads();

    float4v acc[2][4] = {};                           // [mf(oc16)][py]
    #pragma unroll
    for (int ks = 0; ks < 2; ++ks) {
        short8 Aw[9][2];
        #pragma unroll
        for (int s = 0; s < 9; ++s)
            #pragma unroll
            for (int mf = 0; mf < 2; ++mf) {
                int oc = ohalf * 32 + mf * 16 + l15;
                Aw[s][mf] = *(const short8*)(rw2 + ((s * 64 + oc) * 64 + ks * 32 + quad * 8));
            }
        #pragma unroll
        for (int r = 0; r < 6; ++r) {
            int slabrow = rhalf * 4 + r;
            short8 Bx[3];
            #pragma unroll
            for (int kx = 0; kx < 3; ++kx)
                Bx[kx] = *(const short8*)(&sX[(slabrow * 18 + l15 + kx) * 72 + ks * 32 + quad * 8]);
            #pragma unroll
            for (int ky = 0; ky < 3; ++ky) {
                int py = r - ky;
                if (py >= 0 && py < 4) {
                    #pragma unroll
                    for (int kx = 0; kx < 3; ++kx)
                        #pragma unroll
                        for (int mf = 0; mf < 2; ++mf)
                            acc[mf][py] = MFMA_B16(Aw[ky * 3 + kx][mf], Bx[kx], acc[mf][py]);
                }
            }
        }
    }
    // epilogue: D oc = ohalf*32+mf*16+quad*4+reg, px = l15 -> f32 NCHW
    #pragma unroll
    for (int mf = 0; mf < 2; ++mf)
        #pragma unroll
        for (int reg = 0; reg < 4; ++reg) {
            int oc = ohalf * 32 + mf * 16 + quad * 4 + reg;
            float bias = b2[oc];
            #pragma unroll
            for (int py = 0; py < 4; ++py) {
                int gy = py0 + rhalf * 4 + py, gx = px0 + l15;
                size_t idx = (((size_t)(b * 64 + oc)) << 14) + gy * 128 + gx;
                outres[idx] = acc[mf][py][reg] + bias + outres[idx];
            }
        }
}

// ---------------------------------------------------------------------------
extern "C" void kernel_launch(void* const* d_in, const int* in_sizes, int n_in,
                              void* d_out, int out_size, void* d_ws, size_t ws_size,
                              hipStream_t stream) {
    const float* o      = (const float*)d_in[0];
    const float* anchor = (const float*)d_in[1];
    const float* pw     = (const float*)d_in[2];
    const float* pb     = (const float*)d_in[3];
    const float* mw     = (const float*)d_in[4];
    const float* mb     = (const float*)d_in[5];
    const float* cw     = (const float*)d_in[6];
    const float* w1     = (const float*)d_in[7];
    const float* b1     = (const float*)d_in[8];
    const float* w2     = (const float*)d_in[9];
    const float* b2     = (const float*)d_in[10];
    float* out = (float*)d_out;

    char* ws = (char*)d_ws;
    ushort* anc_nhwc = (ushort*)(ws);                  // 8,388,608 B
    ushort* xcatA    = (ushort*)(ws + 8388608);        // 8,388,608 B
    ushort* t1b      = (ushort*)(ws + 16777216);       // 8,388,608 B
    char*   wsm      = ws + 25165824;
    ushort* rw1p     = (ushort*)(wsm);                 // 147,456 B
    ushort* rw2p     = (ushort*)(wsm + 147456);        // 73,728 B
    ushort* rpwh     = (ushort*)(wsm + 147456 + 73728);            // 49,152 B
    ushort* rpwl     = (ushort*)(wsm + 147456 + 73728 + 49152);    // 49,152 B
    ushort* rcwp     = (ushort*)(wsm + 147456 + 73728 + 98304);    // 24,576 B

    repack_weights<<<288, 256, 0, stream>>>(w1, w2, pw, pb, mw, mb, cw,
                                            rw1p, rw2p, rpwh, rpwl, rcwp);
    to_nhwc<<<dim3(64, 4), 256, 0, stream>>>(anchor, anc_nhwc);
    deform_mfma<<<dim3(64, 8, 4), 256, 0, stream>>>(o, anc_nhwc, rpwh, rpwl, rcwp,
                                                    xcatA, out /*target*/);
    conv1_mfma<<<dim3(128, 4), 256, 0, stream>>>(xcatA, anc_nhwc, rw1p, b1, t1b);
    conv2_mfma<<<dim3(128, 4), 256, 0, stream>>>(t1b, rw2p, b2, out);
}

// Round 4
// 198.456 us; speedup vs baseline: 2.8444x; 1.0501x over previous
//
#include <hip/hip_runtime.h>

// ============================================================================
// MotionCompensation on MI355X — bf16 MFMA pipeline, round 4.
// r4 changes: deform LDS union (64KB->53KB => 3 blocks/CU), barriers 6->3,
// batched phase-B gathers (12 loads in flight), __expf sigmoid, conv1/conv2
// register double-buffered weight fragments, repack+to_nhwc fused.
// ============================================================================

typedef __attribute__((ext_vector_type(8))) short short8;
typedef __attribute__((ext_vector_type(4))) float float4v;

#define MFMA_B16(a, b, c) __builtin_amdgcn_mfma_f32_16x16x32_bf16(a, b, c, 0, 0, 0)

__device__ __forceinline__ ushort f2bf(float f) {          // RNE f32 -> bf16
    union { float f; unsigned u; } v; v.f = f;
    unsigned r = v.u + 0x7FFFu + ((v.u >> 16) & 1u);
    return (ushort)(r >> 16);
}
__device__ __forceinline__ float bf2f(ushort h) {
    union { unsigned u; float f; } v; v.u = ((unsigned)h) << 16;
    return v.f;
}

// ---------------------------------------------------------------------------
// prep: fused {NCHW f32 -> NHWC bf16 anchor transform} + {weight repack}.
// blocks 0..255: to_nhwc; blocks 256..543: repack.
//   rw1[s9][oc64][ic128]  rw2[s9][oc64][ic64]  (bf16)
//   rpwh/rpwl[g8][n32][k96]  hi/lo split (n: 0-8 ox, 9-17 oy, 18-26 mz;
//                            k = s*8+ic, k==72 bias)
//   rcw[g8][oc16][k96] (k = n*8+ic)
// ---------------------------------------------------------------------------
__global__ __launch_bounds__(256) void prep(
    const float* __restrict__ anchor,
    const float* __restrict__ w1, const float* __restrict__ w2,
    const float* __restrict__ pw, const float* __restrict__ pb,
    const float* __restrict__ mw, const float* __restrict__ mb,
    const float* __restrict__ cw,
    ushort* __restrict__ anc_nhwc,
    ushort* __restrict__ rw1, ushort* __restrict__ rw2,
    ushort* __restrict__ rpwh, ushort* __restrict__ rpwl,
    ushort* __restrict__ rcw)
{
    const int blk = blockIdx.x;
    if (blk < 256) {                       // ---- to_nhwc
        int pix = (blk & 63) * 256 + threadIdx.x;
        int b = blk >> 6;
        ushort tmp[64];
        #pragma unroll
        for (int ch = 0; ch < 64; ++ch)
            tmp[ch] = f2bf(anchor[(((size_t)(b * 64 + ch)) << 14) + pix]);
        ushort* dp = anc_nhwc + (((size_t)b) << 20) + (size_t)pix * 64;
        #pragma unroll
        for (int grp = 0; grp < 8; ++grp) {
            short8 v;
            #pragma unroll
            for (int j = 0; j < 8; ++j) v[j] = (short)tmp[grp * 8 + j];
            *(short8*)(dp + grp * 8) = v;
        }
        return;
    }
    int i = (blk - 256) * 256 + threadIdx.x;   // ---- repack
    if (i < 73728) {                       // rw1
        int ic = i & 127, r = i >> 7, oc = r & 63, s = r >> 6;
        rw1[i] = f2bf(w1[(oc * 128 + ic) * 9 + s]);
    }
    if (i < 36864) {                       // rw2
        int ic = i & 63, r = i >> 6, oc = r & 63, s = r >> 6;
        rw2[i] = f2bf(w2[(oc * 64 + ic) * 9 + s]);
    }
    if (i < 24576) {                       // rpw hi/lo
        int k = i % 96, r = i / 96, n = r & 31, g = r >> 5;
        float v = 0.f;
        if (k < 72) {
            int s = k >> 3, ic = k & 7;
            if (n < 18)      v = pw[((g * 18 + n) * 8 + ic) * 9 + s];
            else if (n < 27) v = mw[((g * 9 + (n - 18)) * 8 + ic) * 9 + s];
        } else if (k == 72) {
            if (n < 18)      v = pb[g * 18 + n];
            else if (n < 27) v = mb[g * 9 + (n - 18)];
        }
        ushort h = f2bf(v);
        rpwh[i] = h;
        rpwl[i] = f2bf(v - bf2f(h));
    }
    if (i < 12288) {                       // rcw
        int k = i % 96, r = i / 96, oc = r & 15, g = r >> 4;
        float v = 0.f;
        if (k < 72 && oc < 8) {
            int n = k >> 3, ic = k & 7;
            v = cw[((g * 8 + oc) * 8 + ic) * 9 + n];
        }
        rcw[i] = f2bf(v);
    }
}

// ---------------------------------------------------------------------------
// Deformable stage. LDS union (53,248 B => 3 blocks/CU):
//   [0      .. 5184)  slabh   (phase A only)
//   [5184   ..10368)  slabl   (phase A only)
//   [16384  ..50176)  sOff    (phase A output -> phase B input)
//   [0      ..53248)  sS      (phase B output -> phase C; stride 104 ushort)
// Barriers: after slab stage, after sOff writes, after offset reads. Phase
// B->C handoff and phase-C bounce are wave-private LDS rows (no barrier).
// ---------------------------------------------------------------------------
__global__ __launch_bounds__(256, 3) void deform_mfma(
    const float* __restrict__ o, const ushort* __restrict__ anc,
    const ushort* __restrict__ rpwh, const ushort* __restrict__ rpwl,
    const ushort* __restrict__ rcw,
    ushort* __restrict__ xcatA, float* __restrict__ target)
{
    const int tile = blockIdx.x, g = blockIdx.y, b = blockIdx.z;
    const int ty0 = (tile >> 3) * 16, tx0 = (tile & 7) * 16;
    const int tid = threadIdx.x, lane = tid & 63, wave = tid >> 6;
    const int l15 = lane & 15, quad = lane >> 4;

    __shared__ __align__(16) ushort sU[26624];        // 53,248 B union
    ushort* slabh = sU;                               // 18x18 halo, 8ch, hi
    ushort* slabl = sU + 2592;                        // lo
    float*  sOff  = (float*)(sU + 8192);              // 256 px * 33 f32

    const size_t nbase = ((size_t)b) << 20;           // per-image NHWC elems

    for (int idx = tid; idx < 8 * 324; idx += 256) {
        int ic = idx / 324; int pix = idx - ic * 324;
        int r = pix / 18, c = pix - r * 18;
        int gy = ty0 + r - 1, gx = tx0 + c - 1;
        float v = 0.f;
        if ((unsigned)gy < 128u && (unsigned)gx < 128u)
            v = o[(((size_t)(b * 64 + g * 8 + ic)) << 14) + (gy << 7) + gx];
        ushort h = f2bf(v);
        slabh[pix * 8 + ic] = h;
        slabl[pix * 8 + ic] = f2bf(v - bf2f(h));
    }
    __syncthreads();                                  // barrier 1

    // ---- phase A: offsets/mask conv (27 out ch padded to 32), hi/lo split
    float4v offacc[4][2] = {};
    #pragma unroll
    for (int ks = 0; ks < 3; ++ks) {
        short8 Bh[2], Bl[2];
        #pragma unroll
        for (int nf = 0; nf < 2; ++nf) {
            int off = (g * 32 + nf * 16 + l15) * 96 + ks * 32 + quad * 8;
            Bh[nf] = *(const short8*)(rpwh + off);
            Bl[nf] = *(const short8*)(rpwl + off);
        }
        short8 Ah[4], Al[4];
        if (ks < 2) {
            int s = ks * 4 + quad, sy = s / 3, sx = s - sy * 3;
            #pragma unroll
            for (int py = 0; py < 4; ++py) {
                int row = wave * 4 + py;
                int sl = ((row + sy) * 18 + l15 + sx) * 8;
                Ah[py] = *(const short8*)(&slabh[sl]);
                Al[py] = *(const short8*)(&slabl[sl]);
            }
        } else {  // k 64-71: tap s=8 (quad0); k72: bias one-hot (quad1)
            #pragma unroll
            for (int py = 0; py < 4; ++py) {
                short8 zh = {0, 0, 0, 0, 0, 0, 0, 0};
                short8 zl = {0, 0, 0, 0, 0, 0, 0, 0};
                if (quad == 0) {
                    int row = wave * 4 + py;
                    int sl = ((row + 2) * 18 + l15 + 2) * 8;
                    zh = *(const short8*)(&slabh[sl]);
                    zl = *(const short8*)(&slabl[sl]);
                } else if (quad == 1) {
                    zh[0] = (short)0x3F80;  // bf16 1.0 (bias column)
                }
                Ah[py] = zh; Al[py] = zl;
            }
        }
        #pragma unroll
        for (int py = 0; py < 4; ++py)
            #pragma unroll
            for (int nf = 0; nf < 2; ++nf) {
                offacc[py][nf] = MFMA_B16(Ah[py], Bh[nf], offacc[py][nf]);
                offacc[py][nf] = MFMA_B16(Ah[py], Bl[nf], offacc[py][nf]);
                offacc[py][nf] = MFMA_B16(Al[py], Bh[nf], offacc[py][nf]);
            }
    }
    // bounce D (px = quad*4+reg, ch = nf*16+l15) -> sOff[p][33] (disjoint from slab)
    #pragma unroll
    for (int py = 0; py < 4; ++py) {
        int p0 = (wave * 4 + py) * 16 + quad * 4;
        #pragma unroll
        for (int nf = 0; nf < 2; ++nf)
            #pragma unroll
            for (int reg = 0; reg < 4; ++reg)
                sOff[(p0 + reg) * 33 + nf * 16 + l15] = offacc[py][nf][reg];
    }
    __syncthreads();                                  // barrier 2

    const int p = tid;
    const int gy = ty0 + (p >> 4), gx = tx0 + (p & 15);
    float ox[9], oy[9], mz[9];
    #pragma unroll
    for (int n = 0; n < 9; ++n) {
        ox[n] = sOff[p * 33 + n];
        oy[n] = sOff[p * 33 + 9 + n];
        mz[n] = sOff[p * 33 + 18 + n];
    }
    __syncthreads();                                  // barrier 3 (sOff -> sS reuse)

    // ---- phase B: bilinear sampling -> sS[p][k=n*8+ic] bf16 (stride 104)
    // Batched 3 taps at a time: 12 gathers in flight per waitcnt.
    const ushort* ab = anc + nbase + g * 8;
    #pragma unroll
    for (int nb = 0; nb < 3; ++nb) {
        float Wlt[3], Wrb[3], Wlb[3], Wrt[3];
        short8 vlt[3], vrb[3], vlb[3], vrt[3];
        #pragma unroll
        for (int j = 0; j < 3; ++j) {
            const int n = nb * 3 + j;
            float pxf = (float)(gy + n / 3) + ox[n];
            float pyf = (float)(gx + n % 3) + oy[n];
            float fx = floorf(pxf), fy = floorf(pyf);
            float qxl = fminf(fmaxf(fx, 0.f), 127.f);
            float qxr = fminf(fmaxf(fx + 1.f, 0.f), 127.f);
            float qyl = fminf(fmaxf(fy, 0.f), 127.f);
            float qyr = fminf(fmaxf(fy + 1.f, 0.f), 127.f);
            float pxc = fminf(fmaxf(pxf, 0.f), 127.f);
            float pyc = fminf(fmaxf(pyf, 0.f), 127.f);
            float glx = 1.f + (qxl - pxc), grx = 1.f - (qxr - pxc);
            float gly = 1.f + (qyl - pyc), gry = 1.f - (qyr - pyc);
            float mm = 1.f / (1.f + __expf(-mz[n]));
            Wlt[j] = glx * gly * mm; Wrb[j] = grx * gry * mm;
            Wlb[j] = glx * gry * mm; Wrt[j] = grx * gly * mm;
            int ixl = (int)qxl, ixr = (int)qxr, iyl = (int)qyl, iyr = (int)qyr;
            vlt[j] = *(const short8*)(ab + (size_t)(ixl * 128 + iyl) * 64);
            vrb[j] = *(const short8*)(ab + (size_t)(ixr * 128 + iyr) * 64);
            vlb[j] = *(const short8*)(ab + (size_t)(ixl * 128 + iyr) * 64);
            vrt[j] = *(const short8*)(ab + (size_t)(ixr * 128 + iyl) * 64);
        }
        #pragma unroll
        for (int j = 0; j < 3; ++j) {
            const int n = nb * 3 + j;
            short8 sv;
            #pragma unroll
            for (int ic = 0; ic < 8; ++ic) {
                float val = Wlt[j] * bf2f((ushort)vlt[j][ic])
                          + Wrb[j] * bf2f((ushort)vrb[j][ic])
                          + Wlb[j] * bf2f((ushort)vlb[j][ic])
                          + Wrt[j] * bf2f((ushort)vrt[j][ic]);
                sv[ic] = (short)f2bf(val);
            }
            *(short8*)(&sU[p * 104 + n * 8]) = sv;
        }
    }
    {
        short8 z = {0, 0, 0, 0, 0, 0, 0, 0};
        *(short8*)(&sU[p * 104 + 72]) = z;
        *(short8*)(&sU[p * 104 + 80]) = z;
        *(short8*)(&sU[p * 104 + 88]) = z;
    }
    // no barrier: phase C reads only this wave's 64 rows

    // ---- phase C: group conv, N = 16 (8 used), K = 96 (72 used)
    float4v cacc[4] = {};
    #pragma unroll
    for (int ks = 0; ks < 3; ++ks) {
        short8 Bw = *(const short8*)(rcw + ((g * 16 + l15) * 96 + ks * 32 + quad * 8));
        #pragma unroll
        for (int py = 0; py < 4; ++py) {
            int pp = (wave * 4 + py) * 16 + l15;
            short8 Af = *(const short8*)(&sU[pp * 104 + ks * 32 + quad * 8]);
            cacc[py] = MFMA_B16(Af, Bw, cacc[py]);
        }
    }
    // bounce D (px = quad*4+reg, oc = l15<8) into own wave's rows (no barrier)
    #pragma unroll
    for (int py = 0; py < 4; ++py) {
        int pr = (wave * 4 + py) * 16 + quad * 4;
        if (l15 < 8) {
            #pragma unroll
            for (int reg = 0; reg < 4; ++reg)
                ((float*)&sU[(pr + reg) * 104])[l15] = cacc[py][reg];
        }
    }
    float res[8];
    #pragma unroll
    for (int oc = 0; oc < 8; ++oc) res[oc] = ((float*)&sU[p * 104])[oc];

    short8 pk;
    #pragma unroll
    for (int oc = 0; oc < 8; ++oc) pk[oc] = (short)f2bf(res[oc]);
    *(short8*)(xcatA + nbase + (size_t)(gy * 128 + gx) * 64 + g * 8) = pk;
    #pragma unroll
    for (int oc = 0; oc < 8; ++oc)
        target[(((size_t)(b * 64 + g * 8 + oc)) << 14) + gy * 128 + gx] = res[oc];
}

// ---------------------------------------------------------------------------
// conv1: 3x3, cin=128 (xcatA ch0-63 | anchor ch64-127), cout=64, +bias.
// Implicit GEMM; B fragments register double-buffered across ks chunks.
// ---------------------------------------------------------------------------
__global__ __launch_bounds__(256, 2) void conv1_mfma(
    const ushort* __restrict__ xA, const ushort* __restrict__ xB,
    const ushort* __restrict__ rw1, const float* __restrict__ b1,
    ushort* __restrict__ t1)
{
    const int patch = blockIdx.x, b = blockIdx.y;
    const int px0 = (patch & 7) * 16, py0 = (patch >> 3) * 8;
    const int tid = threadIdx.x, lane = tid & 63, wave = tid >> 6;
    const int mhalf = wave & 1, nhalf = wave >> 1;
    const int l15 = lane & 15, quad = lane >> 4;

    __shared__ __align__(16) ushort sA[180 * 136];    // 18x10 halo, 128ch +8 pad

    // preload ks=0 B fragments (overlaps with staging + barrier)
    short8 Bc[9][2];
    #pragma unroll
    for (int s = 0; s < 9; ++s)
        #pragma unroll
        for (int nf = 0; nf < 2; ++nf) {
            int oc = nhalf * 32 + nf * 16 + l15;
            Bc[s][nf] = *(const short8*)(rw1 + ((s * 64 + oc) * 128 + quad * 8));
        }

    const size_t nbase = ((size_t)b) << 20;
    for (int task = tid; task < 2880; task += 256) {  // 180 px * 16 ch-groups
        int pix = task >> 4, grp = task & 15;
        int r = pix / 18, c = pix - r * 18;
        int gy = py0 + r - 1, gx = px0 + c - 1;
        short8 v = {0, 0, 0, 0, 0, 0, 0, 0};
        if ((unsigned)gy < 128u && (unsigned)gx < 128u) {
            const ushort* src = (grp < 8) ? xA : xB;
            v = *(const short8*)(src + nbase + (size_t)(gy * 128 + gx) * 64 + (grp & 7) * 8);
        }
        *(short8*)(&sA[pix * 136 + grp * 8]) = v;
    }
    __syncthreads();

    float4v acc[4][2] = {};                           // [py][nf]
    #pragma unroll
    for (int ks = 0; ks < 4; ++ks) {
        short8 Bn[9][2];
        if (ks < 3) {                                 // prefetch next ks chunk
            #pragma unroll
            for (int s = 0; s < 9; ++s)
                #pragma unroll
                for (int nf = 0; nf < 2; ++nf) {
                    int oc = nhalf * 32 + nf * 16 + l15;
                    Bn[s][nf] = *(const short8*)(rw1 + ((s * 64 + oc) * 128 + (ks + 1) * 32 + quad * 8));
                }
        }
        #pragma unroll
        for (int r = 0; r < 6; ++r) {                 // slab row = py + ky
            int slabrow = mhalf * 4 + r;
            short8 A[3];
            #pragma unroll
            for (int kx = 0; kx < 3; ++kx)
                A[kx] = *(const short8*)(&sA[(slabrow * 18 + l15 + kx) * 136 + ks * 32 + quad * 8]);
            #pragma unroll
            for (int ky = 0; ky < 3; ++ky) {
                int py = r - ky;
                if (py >= 0 && py < 4) {
                    #pragma unroll
                    for (int kx = 0; kx < 3; ++kx)
                        #pragma unroll
                        for (int nf = 0; nf < 2; ++nf)
                            acc[py][nf] = MFMA_B16(A[kx], Bc[ky * 3 + kx][nf], acc[py][nf]);
                }
            }
        }
        if (ks < 3) {
            #pragma unroll
            for (int s = 0; s < 9; ++s)
                #pragma unroll
                for (int nf = 0; nf < 2; ++nf) Bc[s][nf] = Bn[s][nf];
        }
    }
    // epilogue: D px = quad*4+reg, oc = nhalf*32+nf*16+l15 -> t1 NHWC bf16
    #pragma unroll
    for (int nf = 0; nf < 2; ++nf) {
        int oc = nhalf * 32 + nf * 16 + l15;
        float bias = b1[oc];
        #pragma unroll
        for (int py = 0; py < 4; ++py) {
            int gy = py0 + mhalf * 4 + py;
            #pragma unroll
            for (int reg = 0; reg < 4; ++reg) {
                int gx = px0 + quad * 4 + reg;
                t1[nbase + (size_t)(gy * 128 + gx) * 64 + oc] = f2bf(acc[py][nf][reg] + bias);
            }
        }
    }
}

// ---------------------------------------------------------------------------
// conv2: 3x3, cin=64 (t1), cout=64, +bias +residual(target). A = weights so
// D[oc][px] -> coalesced f32 NCHW stores. Weight frags double-buffered.
// ---------------------------------------------------------------------------
__global__ __launch_bounds__(256, 2) void conv2_mfma(
    const ushort* __restrict__ t1, const ushort* __restrict__ rw2,
    const float* __restrict__ b2, float* outres)
{
    const int patch = blockIdx.x, b = blockIdx.y;
    const int px0 = (patch & 7) * 16, py0 = (patch >> 3) * 8;
    const int tid = threadIdx.x, lane = tid & 63, wave = tid >> 6;
    const int ohalf = wave & 1, rhalf = wave >> 1;
    const int l15 = lane & 15, quad = lane >> 4;

    __shared__ __align__(16) ushort sX[180 * 72];     // 18x10 halo, 64ch +8 pad

    short8 Ac[9][2];                                  // preload ks=0
    #pragma unroll
    for (int s = 0; s < 9; ++s)
        #pragma unroll
        for (int mf = 0; mf < 2; ++mf) {
            int oc = ohalf * 32 + mf * 16 + l15;
            Ac[s][mf] = *(const short8*)(rw2 + ((s * 64 + oc) * 64 + quad * 8));
        }

    const size_t nbase = ((size_t)b) << 20;
    for (int task = tid; task < 1440; task += 256) {  // 180 px * 8 ch-groups
        int pix = task >> 3, grp = task & 7;
        int r = pix / 18, c = pix - r * 18;
        int gy = py0 + r - 1, gx = px0 + c - 1;
        short8 v = {0, 0, 0, 0, 0, 0, 0, 0};
        if ((unsigned)gy < 128u && (unsigned)gx < 128u)
            v = *(const short8*)(t1 + nbase + (size_t)(gy * 128 + gx) * 64 + grp * 8);
        *(short8*)(&sX[pix * 72 + grp * 8]) = v;
    }
    __syncthreads();

    float4v acc[2][4] = {};                           // [mf(oc16)][py]
    #pragma unroll
    for (int ks = 0; ks < 2; ++ks) {
        short8 An[9][2];
        if (ks < 1) {
            #pragma unroll
            for (int s = 0; s < 9; ++s)
                #pragma unroll
                for (int mf = 0; mf < 2; ++mf) {
                    int oc = ohalf * 32 + mf * 16 + l15;
                    An[s][mf] = *(const short8*)(rw2 + ((s * 64 + oc) * 64 + 32 + quad * 8));
                }
        }
        #pragma unroll
        for (int r = 0; r < 6; ++r) {
            int slabrow = rhalf * 4 + r;
            short8 Bx[3];
            #pragma unroll
            for (int kx = 0; kx < 3; ++kx)
                Bx[kx] = *(const short8*)(&sX[(slabrow * 18 + l15 + kx) * 72 + ks * 32 + quad * 8]);
            #pragma unroll
            for (int ky = 0; ky < 3; ++ky) {
                int py = r - ky;
                if (py >= 0 && py < 4) {
                    #pragma unroll
                    for (int kx = 0; kx < 3; ++kx)
                        #pragma unroll
                        for (int mf = 0; mf < 2; ++mf)
                            acc[mf][py] = MFMA_B16(Ac[ky * 3 + kx][mf], Bx[kx], acc[mf][py]);
                }
            }
        }
        if (ks < 1) {
            #pragma unroll
            for (int s = 0; s < 9; ++s)
                #pragma unroll
                for (int mf = 0; mf < 2; ++mf) Ac[s][mf] = An[s][mf];
        }
    }
    // epilogue: D oc = ohalf*32+mf*16+quad*4+reg, px = l15 -> f32 NCHW
    #pragma unroll
    for (int mf = 0; mf < 2; ++mf)
        #pragma unroll
        for (int reg = 0; reg < 4; ++reg) {
            int oc = ohalf * 32 + mf * 16 + quad * 4 + reg;
            float bias = b2[oc];
            #pragma unroll
            for (int py = 0; py < 4; ++py) {
                int gy = py0 + rhalf * 4 + py, gx = px0 + l15;
                size_t idx = (((size_t)(b * 64 + oc)) << 14) + gy * 128 + gx;
                outres[idx] = acc[mf][py][reg] + bias + outres[idx];
            }
        }
}

// ---------------------------------------------------------------------------
extern "C" void kernel_launch(void* const* d_in, const int* in_sizes, int n_in,
                              void* d_out, int out_size, void* d_ws, size_t ws_size,
                              hipStream_t stream) {
    const float* o      = (const float*)d_in[0];
    const float* anchor = (const float*)d_in[1];
    const float* pw     = (const float*)d_in[2];
    const float* pb     = (const float*)d_in[3];
    const float* mw     = (const float*)d_in[4];
    const float* mb     = (const float*)d_in[5];
    const float* cw     = (const float*)d_in[6];
    const float* w1     = (const float*)d_in[7];
    const float* b1     = (const float*)d_in[8];
    const float* w2     = (const float*)d_in[9];
    const float* b2     = (const float*)d_in[10];
    float* out = (float*)d_out;

    char* ws = (char*)d_ws;
    ushort* anc_nhwc = (ushort*)(ws);                  // 8,388,608 B
    ushort* xcatA    = (ushort*)(ws + 8388608);        // 8,388,608 B
    ushort* t1b      = (ushort*)(ws + 16777216);       // 8,388,608 B
    char*   wsm      = ws + 25165824;
    ushort* rw1p     = (ushort*)(wsm);                 // 147,456 B
    ushort* rw2p     = (ushort*)(wsm + 147456);        // 73,728 B
    ushort* rpwh     = (ushort*)(wsm + 147456 + 73728);            // 49,152 B
    ushort* rpwl     = (ushort*)(wsm + 147456 + 73728 + 49152);    // 49,152 B
    ushort* rcwp     = (ushort*)(wsm + 147456 + 73728 + 98304);    // 24,576 B

    prep<<<544, 256, 0, stream>>>(anchor, w1, w2, pw, pb, mw, mb, cw,
                                  anc_nhwc, rw1p, rw2p, rpwh, rpwl, rcwp);
    deform_mfma<<<dim3(64, 8, 4), 256, 0, stream>>>(o, anc_nhwc, rpwh, rpwl, rcwp,
                                                    xcatA, out /*target*/);
    conv1_mfma<<<dim3(128, 4), 256, 0, stream>>>(xcatA, anc_nhwc, rw1p, b1, t1b);
    conv2_mfma<<<dim3(128, 4), 256, 0, stream>>>(t1b, rw2p, b2, out);
}

// Round 5
// 181.366 us; speedup vs baseline: 3.1124x; 1.0942x over previous
//
#include <hip/hip_runtime.h>

// ============================================================================
// MotionCompensation on MI355X — round 5.
// r5: grouped anchor/xcat layouts [b][g][h][w][8ch] (16-B pixel stride =>
// intra-wave cache-line merging for deform gathers); deform phase-B samples
// land directly in MFMA A-fragments (no sS LDS bounce, LDS 53k->38k,
// 4 blocks/CU); epilogue bounced through dead slab LDS for coalesced stores.
// ============================================================================

typedef __attribute__((ext_vector_type(8))) short short8;
typedef __attribute__((ext_vector_type(4))) float float4v;

#define MFMA_B16(a, b, c) __builtin_amdgcn_mfma_f32_16x16x32_bf16(a, b, c, 0, 0, 0)

__device__ __forceinline__ ushort f2bf(float f) {          // RNE f32 -> bf16
    union { float f; unsigned u; } v; v.f = f;
    unsigned r = v.u + 0x7FFFu + ((v.u >> 16) & 1u);
    return (ushort)(r >> 16);
}
__device__ __forceinline__ float bf2f(ushort h) {
    union { unsigned u; float f; } v; v.u = ((unsigned)h) << 16;
    return v.f;
}

// weights+offsets for one deformable tap (4 corners)
__device__ __forceinline__ void tap_wo(int gy, int gx, int n,
                                       float ox, float oy, float mzv,
                                       float* W, int* O)
{
    int ky = n / 3, kx = n - ky * 3;
    float pxf = (float)(gy + ky) + ox;
    float pyf = (float)(gx + kx) + oy;
    float fx = floorf(pxf), fy = floorf(pyf);
    float qxl = fminf(fmaxf(fx, 0.f), 127.f);
    float qxr = fminf(fmaxf(fx + 1.f, 0.f), 127.f);
    float qyl = fminf(fmaxf(fy, 0.f), 127.f);
    float qyr = fminf(fmaxf(fy + 1.f, 0.f), 127.f);
    float pxc = fminf(fmaxf(pxf, 0.f), 127.f);
    float pyc = fminf(fmaxf(pyf, 0.f), 127.f);
    float glx = 1.f + (qxl - pxc), grx = 1.f - (qxr - pxc);
    float gly = 1.f + (qyl - pyc), gry = 1.f - (qyr - pyc);
    float mm = 1.f / (1.f + __expf(-mzv));
    W[0] = glx * gly * mm; W[1] = grx * gry * mm;
    W[2] = glx * gry * mm; W[3] = grx * gly * mm;
    int ixl = (int)qxl, ixr = (int)qxr, iyl = (int)qyl, iyr = (int)qyr;
    O[0] = ixl * 128 + iyl; O[1] = ixr * 128 + iyr;
    O[2] = ixl * 128 + iyr; O[3] = ixr * 128 + iyl;
}

__device__ __forceinline__ short8 interp4(const float* W, const short8* cv)
{
    short8 out;
    #pragma unroll
    for (int ic = 0; ic < 8; ++ic) {
        float v = W[0] * bf2f((ushort)cv[0][ic]) + W[1] * bf2f((ushort)cv[1][ic])
                + W[2] * bf2f((ushort)cv[2][ic]) + W[3] * bf2f((ushort)cv[3][ic]);
        out[ic] = (short)f2bf(v);
    }
    return out;
}

// ---------------------------------------------------------------------------
// prep: blocks 0..255: anchor NCHW f32 -> grouped bf16 [b][g][16k px][8ch];
//       blocks 256..543: weight repack (same layouts as r4).
// ---------------------------------------------------------------------------
__global__ __launch_bounds__(256) void prep(
    const float* __restrict__ anchor,
    const float* __restrict__ w1, const float* __restrict__ w2,
    const float* __restrict__ pw, const float* __restrict__ pb,
    const float* __restrict__ mw, const float* __restrict__ mb,
    const float* __restrict__ cw,
    ushort* __restrict__ anc_g,
    ushort* __restrict__ rw1, ushort* __restrict__ rw2,
    ushort* __restrict__ rpwh, ushort* __restrict__ rpwl,
    ushort* __restrict__ rcw)
{
    const int blk = blockIdx.x;
    if (blk < 256) {                       // ---- anchor transform
        int pix = (blk & 63) * 256 + threadIdx.x;
        int b = blk >> 6;
        ushort tmp[64];
        #pragma unroll
        for (int ch = 0; ch < 64; ++ch)
            tmp[ch] = f2bf(anchor[(((size_t)(b * 64 + ch)) << 14) + pix]);
        #pragma unroll
        for (int grp = 0; grp < 8; ++grp) {
            short8 v;
            #pragma unroll
            for (int j = 0; j < 8; ++j) v[j] = (short)tmp[grp * 8 + j];
            *(short8*)(anc_g + ((size_t)(b * 8 + grp)) * 131072 + (size_t)pix * 8) = v;
        }
        return;
    }
    int i = (blk - 256) * 256 + threadIdx.x;   // ---- repack
    if (i < 73728) {                       // rw1[s9][oc64][ic128]
        int ic = i & 127, r = i >> 7, oc = r & 63, s = r >> 6;
        rw1[i] = f2bf(w1[(oc * 128 + ic) * 9 + s]);
    }
    if (i < 36864) {                       // rw2[s9][oc64][ic64]
        int ic = i & 63, r = i >> 6, oc = r & 63, s = r >> 6;
        rw2[i] = f2bf(w2[(oc * 64 + ic) * 9 + s]);
    }
    if (i < 24576) {                       // rpw hi/lo [g][n32][k96]
        int k = i % 96, r = i / 96, n = r & 31, g = r >> 5;
        float v = 0.f;
        if (k < 72) {
            int s = k >> 3, ic = k & 7;
            if (n < 18)      v = pw[((g * 18 + n) * 8 + ic) * 9 + s];
            else if (n < 27) v = mw[((g * 9 + (n - 18)) * 8 + ic) * 9 + s];
        } else if (k == 72) {
            if (n < 18)      v = pb[g * 18 + n];
            else if (n < 27) v = mb[g * 9 + (n - 18)];
        }
        ushort h = f2bf(v);
        rpwh[i] = h;
        rpwl[i] = f2bf(v - bf2f(h));
    }
    if (i < 12288) {                       // rcw[g][oc16][k96]
        int k = i % 96, r = i / 96, oc = r & 15, g = r >> 4;
        float v = 0.f;
        if (k < 72 && oc < 8) {
            int n = k >> 3, ic = k & 7;
            v = cw[((g * 8 + oc) * 8 + ic) * 9 + n];
        }
        rcw[i] = f2bf(v);
    }
}

// ---------------------------------------------------------------------------
// Deformable stage. LDS 38,016 B => 4 blocks/CU:
//   slabh [0,5184) slabl [5184,10368) bytes; sOff f32 x 256x27 [10368,38016);
//   sEp (epilogue, 8 KB) reuses [0,8192) after barrier 2.
// Phase B: thread (quad,l15) samples taps {quad, quad+4} (+8 for quad 0) for
// its wave's 4 pixel rows at column l15 — exactly its MFMA A-frag chunks
// (k = ks*32 + quad*8), so samples go straight into per-py MFMAs. No sS.
// ---------------------------------------------------------------------------
__global__ __launch_bounds__(256, 4) void deform_mfma(
    const float* __restrict__ o, const ushort* __restrict__ anc_g,
    const ushort* __restrict__ rpwh, const ushort* __restrict__ rpwl,
    const ushort* __restrict__ rcw,
    ushort* __restrict__ xcat_g, float* __restrict__ target)
{
    const int tile = blockIdx.x, g = blockIdx.y, b = blockIdx.z;
    const int ty0 = (tile >> 3) * 16, tx0 = (tile & 7) * 16;
    const int tid = threadIdx.x, lane = tid & 63, wave = tid >> 6;
    const int l15 = lane & 15, quad = lane >> 4;

    __shared__ __align__(16) ushort sU[19008];        // 38,016 B
    ushort* slabh = sU;
    ushort* slabl = sU + 2592;
    float*  sOff  = (float*)((char*)sU + 10368);      // 256 px * 27 f32
    float*  sEp   = (float*)sU;                       // epilogue bounce

    // ---- stage o tile 18x18 halo, hi/lo split
    for (int idx = tid; idx < 8 * 324; idx += 256) {
        int ic = idx / 324; int pix = idx - ic * 324;
        int r = pix / 18, c = pix - r * 18;
        int gy = ty0 + r - 1, gx = tx0 + c - 1;
        float v = 0.f;
        if ((unsigned)gy < 128u && (unsigned)gx < 128u)
            v = o[(((size_t)(b * 64 + g * 8 + ic)) << 14) + (gy << 7) + gx];
        ushort h = f2bf(v);
        slabh[pix * 8 + ic] = h;
        slabl[pix * 8 + ic] = f2bf(v - bf2f(h));
    }
    __syncthreads();                                  // barrier 1

    // ---- phase A: offset/mask conv, split-bf16 3-MFMA, 27 ch (pad 32)
    float4v offacc[4][2] = {};
    #pragma unroll
    for (int ks = 0; ks < 3; ++ks) {
        short8 Bh[2], Bl[2];
        #pragma unroll
        for (int nf = 0; nf < 2; ++nf) {
            int off = (g * 32 + nf * 16 + l15) * 96 + ks * 32 + quad * 8;
            Bh[nf] = *(const short8*)(rpwh + off);
            Bl[nf] = *(const short8*)(rpwl + off);
        }
        short8 Ah[4], Al[4];
        if (ks < 2) {
            int s = ks * 4 + quad, sy = s / 3, sx = s - sy * 3;
            #pragma unroll
            for (int py = 0; py < 4; ++py) {
                int row = wave * 4 + py;
                int sl = ((row + sy) * 18 + l15 + sx) * 8;
                Ah[py] = *(const short8*)(&slabh[sl]);
                Al[py] = *(const short8*)(&slabl[sl]);
            }
        } else {  // k 64-71: tap 8 (quad0); k72: bias one-hot (quad1)
            #pragma unroll
            for (int py = 0; py < 4; ++py) {
                short8 zh = {0, 0, 0, 0, 0, 0, 0, 0};
                short8 zl = {0, 0, 0, 0, 0, 0, 0, 0};
                if (quad == 0) {
                    int row = wave * 4 + py;
                    int sl = ((row + 2) * 18 + l15 + 2) * 8;
                    zh = *(const short8*)(&slabh[sl]);
                    zl = *(const short8*)(&slabl[sl]);
                } else if (quad == 1) {
                    zh[0] = (short)0x3F80;  // bf16 1.0 (bias column)
                }
                Ah[py] = zh; Al[py] = zl;
            }
        }
        #pragma unroll
        for (int py = 0; py < 4; ++py)
            #pragma unroll
            for (int nf = 0; nf < 2; ++nf) {
                offacc[py][nf] = MFMA_B16(Ah[py], Bh[nf], offacc[py][nf]);
                offacc[py][nf] = MFMA_B16(Ah[py], Bl[nf], offacc[py][nf]);
                offacc[py][nf] = MFMA_B16(Al[py], Bh[nf], offacc[py][nf]);
            }
    }
    // D (pxcol = quad*4+reg, ch = nf*16+l15) -> sOff[p][27]; same-wave rows
    #pragma unroll
    for (int py = 0; py < 4; ++py) {
        int p0 = (wave * 4 + py) * 16 + quad * 4;
        #pragma unroll
        for (int nf = 0; nf < 2; ++nf) {
            int ch = nf * 16 + l15;
            if (ch < 27) {
                #pragma unroll
                for (int reg = 0; reg < 4; ++reg)
                    sOff[(p0 + reg) * 27 + ch] = offacc[py][nf][reg];
            }
        }
    }
    // no barrier: phase B reads only this wave's own pixel rows

    // ---- phase C B-frags (wave-uniform per lane, L2-hot)
    short8 Bw[3];
    #pragma unroll
    for (int ks = 0; ks < 3; ++ks)
        Bw[ks] = *(const short8*)(rcw + ((g * 16 + l15) * 96 + ks * 32 + quad * 8));

    // ---- phase B+C fused: sample -> A-frag -> MFMA, per pixel row
    const ushort* gb = anc_g + ((size_t)(b * 8 + g)) * 131072;
    const int n1 = quad, n2 = quad + 4;
    float4v cacc[4] = {};
    #pragma unroll
    for (int py = 0; py < 4; ++py) {
        int prow = wave * 4 + py;
        int p = prow * 16 + l15;
        int gy = ty0 + prow, gx = tx0 + l15;

        float W[8]; int O[8];
        tap_wo(gy, gx, n1, sOff[p * 27 + n1], sOff[p * 27 + 9 + n1],
               sOff[p * 27 + 18 + n1], &W[0], &O[0]);
        tap_wo(gy, gx, n2, sOff[p * 27 + n2], sOff[p * 27 + 9 + n2],
               sOff[p * 27 + 18 + n2], &W[4], &O[4]);
        short8 cv[8];
        #pragma unroll
        for (int j = 0; j < 8; ++j)
            cv[j] = *(const short8*)(gb + (size_t)O[j] * 8);
        short8 A0 = interp4(&W[0], &cv[0]);
        short8 A1 = interp4(&W[4], &cv[4]);
        short8 A2 = {0, 0, 0, 0, 0, 0, 0, 0};
        if (quad == 0) {                               // tap 8, 16 lanes only
            float W2[4]; int O2[4];
            tap_wo(gy, gx, 8, sOff[p * 27 + 8], sOff[p * 27 + 17],
                   sOff[p * 27 + 26], W2, O2);
            short8 c2[4];
            #pragma unroll
            for (int j = 0; j < 4; ++j)
                c2[j] = *(const short8*)(gb + (size_t)O2[j] * 8);
            A2 = interp4(W2, c2);
        }
        cacc[py] = MFMA_B16(A0, Bw[0], cacc[py]);
        cacc[py] = MFMA_B16(A1, Bw[1], cacc[py]);
        cacc[py] = MFMA_B16(A2, Bw[2], cacc[py]);
    }

    __syncthreads();                                  // barrier 2 (slab dead)
    // D (pxcol = quad*4+reg, oc = l15<8) -> sEp[p][8]
    #pragma unroll
    for (int py = 0; py < 4; ++py) {
        if (l15 < 8) {
            #pragma unroll
            for (int reg = 0; reg < 4; ++reg)
                sEp[((wave * 4 + py) * 16 + quad * 4 + reg) * 8 + l15] = cacc[py][reg];
        }
    }
    __syncthreads();                                  // barrier 3
    {
        const int p = tid;
        const int gy = ty0 + (p >> 4), gx = tx0 + (p & 15);
        float res[8];
        #pragma unroll
        for (int oc = 0; oc < 8; ++oc) res[oc] = sEp[p * 8 + oc];
        short8 pk;
        #pragma unroll
        for (int oc = 0; oc < 8; ++oc) pk[oc] = (short)f2bf(res[oc]);
        *(short8*)(xcat_g + ((size_t)(b * 8 + g)) * 131072
                   + (size_t)((gy << 7) + gx) * 8) = pk;
        #pragma unroll
        for (int oc = 0; oc < 8; ++oc)
            target[(((size_t)(b * 64 + g * 8 + oc)) << 14) + (gy << 7) + gx] = res[oc];
    }
}

// ---------------------------------------------------------------------------
// conv1: 3x3, cin=128 (xcat_g planes 0-7 | anc_g planes 0-7), cout=64, +bias.
// Staging is plane-major: coalesced 16-B runs within each grouped plane.
// ---------------------------------------------------------------------------
__global__ __launch_bounds__(256, 2) void conv1_mfma(
    const ushort* __restrict__ xg, const ushort* __restrict__ ag,
    const ushort* __restrict__ rw1, const float* __restrict__ b1,
    ushort* __restrict__ t1)
{
    const int patch = blockIdx.x, b = blockIdx.y;
    const int px0 = (patch & 7) * 16, py0 = (patch >> 3) * 8;
    const int tid = threadIdx.x, lane = tid & 63, wave = tid >> 6;
    const int mhalf = wave & 1, nhalf = wave >> 1;
    const int l15 = lane & 15, quad = lane >> 4;

    __shared__ __align__(16) ushort sA[180 * 136];    // 18x10 halo, 128ch +8 pad

    short8 Bc[9][2];                                  // preload ks=0 B frags
    #pragma unroll
    for (int s = 0; s < 9; ++s)
        #pragma unroll
        for (int nf = 0; nf < 2; ++nf) {
            int oc = nhalf * 32 + nf * 16 + l15;
            Bc[s][nf] = *(const short8*)(rw1 + ((s * 64 + oc) * 128 + quad * 8));
        }

    for (int task = tid; task < 2880; task += 256) {  // 16 planes x 180 px
        int grp = task / 180, pix = task - grp * 180;
        int r = pix / 18, c = pix - r * 18;
        int gy = py0 + r - 1, gx = px0 + c - 1;
        short8 v = {0, 0, 0, 0, 0, 0, 0, 0};
        if ((unsigned)gy < 128u && (unsigned)gx < 128u) {
            const ushort* plane = ((grp < 8) ? xg : ag)
                                  + ((size_t)(b * 8 + (grp & 7))) * 131072;
            v = *(const short8*)(plane + (size_t)((gy << 7) + gx) * 8);
        }
        *(short8*)(&sA[pix * 136 + grp * 8]) = v;
    }
    __syncthreads();

    float4v acc[4][2] = {};                           // [py][nf]
    #pragma unroll
    for (int ks = 0; ks < 4; ++ks) {
        short8 Bn[9][2];
        if (ks < 3) {                                 // prefetch next ks chunk
            #pragma unroll
            for (int s = 0; s < 9; ++s)
                #pragma unroll
                for (int nf = 0; nf < 2; ++nf) {
                    int oc = nhalf * 32 + nf * 16 + l15;
                    Bn[s][nf] = *(const short8*)(rw1 + ((s * 64 + oc) * 128 + (ks + 1) * 32 + quad * 8));
                }
        }
        #pragma unroll
        for (int r = 0; r < 6; ++r) {                 // slab row = py + ky
            int slabrow = mhalf * 4 + r;
            short8 A[3];
            #pragma unroll
            for (int kx = 0; kx < 3; ++kx)
                A[kx] = *(const short8*)(&sA[(slabrow * 18 + l15 + kx) * 136 + ks * 32 + quad * 8]);
            #pragma unroll
            for (int ky = 0; ky < 3; ++ky) {
                int py = r - ky;
                if (py >= 0 && py < 4) {
                    #pragma unroll
                    for (int kx = 0; kx < 3; ++kx)
                        #pragma unroll
                        for (int nf = 0; nf < 2; ++nf)
                            acc[py][nf] = MFMA_B16(A[kx], Bc[ky * 3 + kx][nf], acc[py][nf]);
                }
            }
        }
        if (ks < 3) {
            #pragma unroll
            for (int s = 0; s < 9; ++s)
                #pragma unroll
                for (int nf = 0; nf < 2; ++nf) Bc[s][nf] = Bn[s][nf];
        }
    }
    const size_t nbase = ((size_t)b) << 20;
    #pragma unroll
    for (int nf = 0; nf < 2; ++nf) {
        int oc = nhalf * 32 + nf * 16 + l15;
        float bias = b1[oc];
        #pragma unroll
        for (int py = 0; py < 4; ++py) {
            int gy = py0 + mhalf * 4 + py;
            #pragma unroll
            for (int reg = 0; reg < 4; ++reg) {
                int gx = px0 + quad * 4 + reg;
                t1[nbase + (size_t)(gy * 128 + gx) * 64 + oc] = f2bf(acc[py][nf][reg] + bias);
            }
        }
    }
}

// ---------------------------------------------------------------------------
// conv2: 3x3, cin=64 (t1 NHWC), cout=64, +bias +residual(target=d_out).
// A = weights => D[oc][px] -> coalesced f32 NCHW stores.
// ---------------------------------------------------------------------------
__global__ __launch_bounds__(256, 2) void conv2_mfma(
    const ushort* __restrict__ t1, const ushort* __restrict__ rw2,
    const float* __restrict__ b2, float* outres)
{
    const int patch = blockIdx.x, b = blockIdx.y;
    const int px0 = (patch & 7) * 16, py0 = (patch >> 3) * 8;
    const int tid = threadIdx.x, lane = tid & 63, wave = tid >> 6;
    const int ohalf = wave & 1, rhalf = wave >> 1;
    const int l15 = lane & 15, quad = lane >> 4;

    __shared__ __align__(16) ushort sX[180 * 72];     // 18x10 halo, 64ch +8 pad

    short8 Ac[9][2];                                  // preload ks=0
    #pragma unroll
    for (int s = 0; s < 9; ++s)
        #pragma unroll
        for (int mf = 0; mf < 2; ++mf) {
            int oc = ohalf * 32 + mf * 16 + l15;
            Ac[s][mf] = *(const short8*)(rw2 + ((s * 64 + oc) * 64 + quad * 8));
        }

    const size_t nbase = ((size_t)b) << 20;
    for (int task = tid; task < 1440; task += 256) {  // 180 px * 8 ch-groups
        int pix = task >> 3, grp = task & 7;
        int r = pix / 18, c = pix - r * 18;
        int gy = py0 + r - 1, gx = px0 + c - 1;
        short8 v = {0, 0, 0, 0, 0, 0, 0, 0};
        if ((unsigned)gy < 128u && (unsigned)gx < 128u)
            v = *(const short8*)(t1 + nbase + (size_t)(gy * 128 + gx) * 64 + grp * 8);
        *(short8*)(&sX[pix * 72 + grp * 8]) = v;
    }
    __syncthreads();

    float4v acc[2][4] = {};                           // [mf(oc16)][py]
    #pragma unroll
    for (int ks = 0; ks < 2; ++ks) {
        short8 An[9][2];
        if (ks < 1) {
            #pragma unroll
            for (int s = 0; s < 9; ++s)
                #pragma unroll
                for (int mf = 0; mf < 2; ++mf) {
                    int oc = ohalf * 32 + mf * 16 + l15;
                    An[s][mf] = *(const short8*)(rw2 + ((s * 64 + oc) * 64 + 32 + quad * 8));
                }
        }
        #pragma unroll
        for (int r = 0; r < 6; ++r) {
            int slabrow = rhalf * 4 + r;
            short8 Bx[3];
            #pragma unroll
            for (int kx = 0; kx < 3; ++kx)
                Bx[kx] = *(const short8*)(&sX[(slabrow * 18 + l15 + kx) * 72 + ks * 32 + quad * 8]);
            #pragma unroll
            for (int ky = 0; ky < 3; ++ky) {
                int py = r - ky;
                if (py >= 0 && py < 4) {
                    #pragma unroll
                    for (int kx = 0; kx < 3; ++kx)
                        #pragma unroll
                        for (int mf = 0; mf < 2; ++mf)
                            acc[mf][py] = MFMA_B16(Ac[ky * 3 + kx][mf], Bx[kx], acc[mf][py]);
                }
            }
        }
        if (ks < 1) {
            #pragma unroll
            for (int s = 0; s < 9; ++s)
                #pragma unroll
                for (int mf = 0; mf < 2; ++mf) Ac[s][mf] = An[s][mf];
        }
    }
    #pragma unroll
    for (int mf = 0; mf < 2; ++mf)
        #pragma unroll
        for (int reg = 0; reg < 4; ++reg) {
            int oc = ohalf * 32 + mf * 16 + quad * 4 + reg;
            float bias = b2[oc];
            #pragma unroll
            for (int py = 0; py < 4; ++py) {
                int gy = py0 + rhalf * 4 + py, gx = px0 + l15;
                size_t idx = (((size_t)(b * 64 + oc)) << 14) + gy * 128 + gx;
                outres[idx] = acc[mf][py][reg] + bias + outres[idx];
            }
        }
}

// ---------------------------------------------------------------------------
extern "C" void kernel_launch(void* const* d_in, const int* in_sizes, int n_in,
                              void* d_out, int out_size, void* d_ws, size_t ws_size,
                              hipStream_t stream) {
    const float* o      = (const float*)d_in[0];
    const float* anchor = (const float*)d_in[1];
    const float* pw     = (const float*)d_in[2];
    const float* pb     = (const float*)d_in[3];
    const float* mw     = (const float*)d_in[4];
    const float* mb     = (const float*)d_in[5];
    const float* cw     = (const float*)d_in[6];
    const float* w1     = (const float*)d_in[7];
    const float* b1     = (const float*)d_in[8];
    const float* w2     = (const float*)d_in[9];
    const float* b2     = (const float*)d_in[10];
    float* out = (float*)d_out;

    char* ws = (char*)d_ws;
    ushort* anc_g  = (ushort*)(ws);                    // 8,388,608 B
    ushort* xcat_g = (ushort*)(ws + 8388608);          // 8,388,608 B
    ushort* t1b    = (ushort*)(ws + 16777216);         // 8,388,608 B
    char*   wsm    = ws + 25165824;
    ushort* rw1p   = (ushort*)(wsm);                   // 147,456 B
    ushort* rw2p   = (ushort*)(wsm + 147456);          // 73,728 B
    ushort* rpwh   = (ushort*)(wsm + 147456 + 73728);             // 49,152 B
    ushort* rpwl   = (ushort*)(wsm + 147456 + 73728 + 49152);     // 49,152 B
    ushort* rcwp   = (ushort*)(wsm + 147456 + 73728 + 98304);     // 24,576 B

    prep<<<544, 256, 0, stream>>>(anchor, w1, w2, pw, pb, mw, mb, cw,
                                  anc_g, rw1p, rw2p, rpwh, rpwl, rcwp);
    deform_mfma<<<dim3(64, 8, 4), 256, 0, stream>>>(o, anc_g, rpwh, rpwl, rcwp,
                                                    xcat_g, out /*target*/);
    conv1_mfma<<<dim3(128, 4), 256, 0, stream>>>(xcat_g, anc_g, rw1p, b1, t1b);
    conv2_mfma<<<dim3(128, 4), 256, 0, stream>>>(t1b, rw2p, b2, out);
}